// Round 1
// 249.326 us; speedup vs baseline: 1.0579x; 1.0579x over previous
//
#include <hip/hip_runtime.h>

#define HID 50
#define IND 8
#define TLEN 512
#define NB 16        // batch columns per block — all 16 MFMA N cols real
#define CH 128       // x chunk timesteps staged in LDS (4 chunks/sequence)
#define XSTR 1032    // x_lds per-column stride in halves (2064B -> 2-way banks)
#define BSTR 72      // B row stride in halves (144B = 36 dw = 4 mod 32: 2-way)
#define NTHR 512     // 8 waves, 2 M-tiles per wave, tiles 0..15 (13 real)

typedef _Float16 f16x8 __attribute__((ext_vector_type(8)));
typedef _Float16 f16x4 __attribute__((ext_vector_type(4)));
typedef float f32x4 __attribute__((ext_vector_type(4)));

__device__ __forceinline__ float fast_sigmoid(float v) {
    float e = __builtin_amdgcn_exp2f(-1.44269504f * v);
    return __builtin_amdgcn_rcpf(1.0f + e);
}
__device__ __forceinline__ float fast_tanh(float v) {
    float e = __builtin_amdgcn_exp2f(2.88539008f * v);
    return 1.0f - 2.0f * __builtin_amdgcn_rcpf(e + 1.0f);
}

// Round-11: 8 waves x 2 M-tiles (was 13 waves x 1 tile).
//  - bf0/bf1 LDS reads shared across a wave's 2 tiles: 16 ds_read_b128/step (was 26)
//  - chained MFMA (bias -> a0*bf0 -> a1*bf1) removes the 4 f32 c+d adds per pair
//  - tiles 13..15 are dead (A cols zero, bias zero) -> branch-free, SIMD-balanced
//  - barrier pool 13 -> 8 waves
__global__ __launch_bounds__(NTHR, 1) void gru_mfma7(
    const float* __restrict__ x,      // [B, T, 8]
    const float* __restrict__ W_ih,   // [150, 8]
    const float* __restrict__ W_hh,   // [150, 50]
    const float* __restrict__ b_ih,   // [150]
    const float* __restrict__ b_hh,   // [150]
    const float* __restrict__ W_out,  // [1, 50]
    const float* __restrict__ b_out,  // [1]
    float* __restrict__ out)          // [B]
{
    const int tid  = threadIdx.x;     // 512 threads = 8 waves
    const int wave = tid >> 6;
    const int lane = tid & 63;
    const int m16  = lane & 15;
    const int quad = lane >> 4;
    const int bb   = blockIdx.x;

    const int t0  = 2 * wave;         // tiles 0..15; R = 16*t + m16; R = 4*jh + g
    const int t1  = 2 * wave + 1;
    const int jh0 = 4 * t0 + quad;    // 8*wave + quad      (<= 59; >=50 is dead)
    const int jh1 = 4 * t1 + quad;    // 8*wave + 4 + quad  (<= 63; >=50 is dead)

    __shared__ _Float16 x_lds[NB * XSTR];       // [n][trel*8+d], 33 KB
    __shared__ _Float16 B_lds[2][16 * BSTR];    // [buf][n][k], 4.6 KB
    __shared__ float    red[NB * 56];           // head scratch, 3.5 KB

    // ---- one-time: A fragments + biases into VGPRs ----
    // A[m=lane&15][k=quad*8+j] (HW-verified layout). x block at k=56..63.
    auto aval = [&](int tt, int k) -> float {
        const int R  = 16 * tt + m16;
        const int rj = R >> 2;
        const int g  = R & 3;
        if (rj >= HID) return 0.f;
        if (g <= 1) {
            if (k < HID) return W_hh[(g * HID + rj) * HID + k];
            if (k >= 56) return W_ih[(g * HID + rj) * IND + (k - 56)];
            return 0.f;
        }
        if (g == 2) return (k < HID) ? W_hh[(2 * HID + rj) * HID + k] : 0.f;
        return (k >= 56) ? W_ih[(2 * HID + rj) * IND + (k - 56)] : 0.f;
    };

    f16x8 a00, a01, a10, a11;
#pragma unroll
    for (int j = 0; j < 8; ++j) {
        a00[j] = (_Float16)aval(t0, quad * 8 + j);
        a01[j] = (_Float16)aval(t0, 32 + quad * 8 + j);
        a10[j] = (_Float16)aval(t1, quad * 8 + j);
        a11[j] = (_Float16)aval(t1, 32 + quad * 8 + j);
    }

    auto mkbias = [&](int jh) -> f32x4 {
        f32x4 b = {0.f, 0.f, 0.f, 0.f};
        if (jh < HID) {
            b[0] = b_ih[jh] + b_hh[jh];
            b[1] = b_ih[HID + jh] + b_hh[HID + jh];
            b[2] = b_hh[2 * HID + jh];
            b[3] = b_ih[2 * HID + jh];
        }
        return b;
    };
    const f32x4 bias0 = mkbias(jh0);
    const f32x4 bias1 = mkbias(jh1);

    float h0 = 0.f, h1 = 0.f;

    // ---- x chunk staging: 128 timesteps, per-column contiguous ----
    auto stage_chunk = [&](int c) {
        const int n = tid >> 5;    // 0..15
        const int s = tid & 31;
        const float4* src = (const float4*)(x + ((size_t)(bb * NB + n) * TLEN + (size_t)c * CH) * IND);
#pragma unroll
        for (int r2 = 0; r2 < 8; ++r2) {
            const int fidx = s + 32 * r2;      // 0..255 float4 per column
            const float4 v = src[fidx];
            const int trel = fidx >> 1;
            const int d    = (fidx & 1) * 4;
            *(f16x4*)&x_lds[n * XSTR + trel * 8 + d] =
                f16x4{(_Float16)v.x, (_Float16)v.y, (_Float16)v.z, (_Float16)v.w};
        }
    };

    // ---- init: zero both B buffers; stage chunk 0 ----
    {
        _Float16* bz = &B_lds[0][0];
        for (int idx = tid; idx < 2 * 16 * BSTR; idx += NTHR)
            bz[idx] = (_Float16)0.f;
    }
    stage_chunk(0);
    __syncthreads();

    const int bq = m16 * BSTR + quad * 8;   // bf0 offset within a buffer
    const int bw = m16 * BSTR;              // h write row base

    auto gates = [&](const f32x4& cc, float h) -> float {
        const float r = fast_sigmoid(cc[0]);
        const float z = fast_sigmoid(cc[1]);
        const float n = fast_tanh(cc[3] + r * cc[2]);
        return n + z * (h - n);
    };

    // ---- the recurrence: 2 tiles per wave, one barrier per step ----
    for (int c = 0; c < 4; ++c) {
        if (c != 0) { stage_chunk(c); __syncthreads(); }
        const _Float16* xb = &x_lds[m16 * XSTR];
        for (int i = 0; i < CH; i += 2) {
            {   // even step: read buf0, write buf1
                const f16x8 bf0 = *(const f16x8*)&B_lds[0][bq];
                const f16x8 bf1 = (quad == 3) ? *(const f16x8*)(xb + (size_t)i * 8)
                                              : *(const f16x8*)&B_lds[0][bq + 32];
                f32x4 c0 = __builtin_amdgcn_mfma_f32_16x16x32_f16(a00, bf0, bias0, 0, 0, 0);
                f32x4 c1 = __builtin_amdgcn_mfma_f32_16x16x32_f16(a10, bf0, bias1, 0, 0, 0);
                c0 = __builtin_amdgcn_mfma_f32_16x16x32_f16(a01, bf1, c0, 0, 0, 0);
                c1 = __builtin_amdgcn_mfma_f32_16x16x32_f16(a11, bf1, c1, 0, 0, 0);
                h0 = gates(c0, h0);
                h1 = gates(c1, h1);
                B_lds[1][bw + jh0] = (_Float16)h0;   // dead rows (>=50) hit zero A cols
                B_lds[1][bw + jh1] = (_Float16)h1;
                __syncthreads();
            }
            {   // odd step: read buf1, write buf0
                const f16x8 bf0 = *(const f16x8*)&B_lds[1][bq];
                const f16x8 bf1 = (quad == 3) ? *(const f16x8*)(xb + (size_t)(i + 1) * 8)
                                              : *(const f16x8*)&B_lds[1][bq + 32];
                f32x4 c0 = __builtin_amdgcn_mfma_f32_16x16x32_f16(a00, bf0, bias0, 0, 0, 0);
                f32x4 c1 = __builtin_amdgcn_mfma_f32_16x16x32_f16(a10, bf0, bias1, 0, 0, 0);
                c0 = __builtin_amdgcn_mfma_f32_16x16x32_f16(a01, bf1, c0, 0, 0, 0);
                c1 = __builtin_amdgcn_mfma_f32_16x16x32_f16(a11, bf1, c1, 0, 0, 0);
                h0 = gates(c0, h0);
                h1 = gates(c1, h1);
                B_lds[0][bw + jh0] = (_Float16)h0;
                B_lds[0][bw + jh1] = (_Float16)h1;
                __syncthreads();
            }
        }
    }

    // ---- head: out[n] = sum_jh h(jh,n) * W_out[jh] + b_out ----
    if (jh0 < HID) red[m16 * 56 + jh0] = h0 * W_out[jh0];
    if (jh1 < HID) red[m16 * 56 + jh1] = h1 * W_out[jh1];
    __syncthreads();
    if (tid < NB) {
        float s = b_out[0];
        for (int j = 0; j < HID; ++j) s += red[tid * 56 + j];
        out[bb * NB + tid] = s;
    }
}

extern "C" void kernel_launch(void* const* d_in, const int* in_sizes, int n_in,
                              void* d_out, int out_size, void* d_ws, size_t ws_size,
                              hipStream_t stream) {
    const float* x     = (const float*)d_in[0];
    const float* W_ih  = (const float*)d_in[1];
    const float* W_hh  = (const float*)d_in[2];
    const float* b_ih  = (const float*)d_in[3];
    const float* b_hh  = (const float*)d_in[4];
    const float* W_out = (const float*)d_in[5];
    const float* b_out = (const float*)d_in[6];
    float* out = (float*)d_out;

    const int B = in_sizes[0] / (TLEN * IND);   // 4096
    gru_mfma7<<<B / NB, NTHR, 0, stream>>>(x, W_ih, W_hh, b_ih, b_hh, W_out, b_out, out);
}

// Round 2
// 242.083 us; speedup vs baseline: 1.0895x; 1.0299x over previous
//
#include <hip/hip_runtime.h>

#define HID 50
#define IND 8
#define TLEN 512
#define NB 16        // batch columns per block — all 16 MFMA N cols real
#define CH 128       // x chunk timesteps staged in LDS (4 chunks/sequence)
#define XSTR 1032    // x_lds per-column stride in halves (2064B -> 2-way banks)
#define BSTR 72      // B row stride in halves; rows 0..49 = h, 56..63 = x(t)
#define NTHR 512     // 8 waves: 0-6 compute tiles, wave 7 copies x into B rows

typedef _Float16 f16x8 __attribute__((ext_vector_type(8)));
typedef _Float16 f16x4 __attribute__((ext_vector_type(4)));
typedef float f32x4 __attribute__((ext_vector_type(4)));

// Round-12:
//  - activation scale constants prefolded into A fragments and biases
//    (r,z rows * -log2(e); n rows * 2*log2(e)) -> no v_mul before exp2
//  - 5-trans gates: h' = (E*(Z+h) + (h-Z)) * rcp((E+1)*(Z+1)),
//    E = 2^(c3 + r*c2), Z = 2^c1, r = rcp(1+2^c0)   (3 exp2 + 2 rcp, was 6 trans)
//  - x(t) stored in B_lds rows 56..63 by wave 7 (its 2 tiles were fully dead):
//    uniform bf1 read (no per-quad select), 14 b128 reads/step (was 16),
//    4 dead MFMAs + 2 dead gate-evals removed
//  - #pragma unroll 4 -> immediate LDS offsets
__global__ __launch_bounds__(NTHR, 1) void gru_mfma8(
    const float* __restrict__ x,      // [B, T, 8]
    const float* __restrict__ W_ih,   // [150, 8]
    const float* __restrict__ W_hh,   // [150, 50]
    const float* __restrict__ b_ih,   // [150]
    const float* __restrict__ b_hh,   // [150]
    const float* __restrict__ W_out,  // [1, 50]
    const float* __restrict__ b_out,  // [1]
    float* __restrict__ out)          // [B]
{
    const int tid  = threadIdx.x;     // 512 threads = 8 waves
    const int wave = tid >> 6;
    const int lane = tid & 63;
    const int m16  = lane & 15;
    const int quad = lane >> 4;
    const int bb   = blockIdx.x;

    const int t0  = 2 * wave;         // tiles 0..13 (waves 0-6); R = 16*t + m16
    const int t1  = 2 * wave + 1;
    const int jh0 = 4 * t0 + quad;    // 8*wave + quad
    const int jh1 = 4 * t1 + quad;    // 8*wave + 4 + quad

    __shared__ _Float16 x_lds[NB * XSTR];       // [n][trel*8+d], 33 KB
    __shared__ _Float16 B_lds[2][16 * BSTR];    // [buf][n][k], 4.6 KB
    __shared__ float    red[NB * 56];           // head scratch, 3.5 KB

    // ---- one-time: A fragments + biases into VGPRs, scales prefolded ----
    // A[m=lane&15][k=quad*8+j] (HW-verified). x block at k=56..63.
    auto aval = [&](int tt, int k) -> float {
        const int R  = 16 * tt + m16;
        const int rj = R >> 2;
        const int g  = R & 3;
        if (rj >= HID) return 0.f;
        const float sc = (g <= 1) ? -1.44269504f : 2.88539008f;
        float w = 0.f;
        if (g <= 1) {
            if (k < HID)      w = W_hh[(g * HID + rj) * HID + k];
            else if (k >= 56) w = W_ih[(g * HID + rj) * IND + (k - 56)];
        } else if (g == 2) {
            if (k < HID)      w = W_hh[(2 * HID + rj) * HID + k];
        } else {
            if (k >= 56)      w = W_ih[(2 * HID + rj) * IND + (k - 56)];
        }
        return sc * w;
    };

    f16x8 a00, a01, a10, a11;
#pragma unroll
    for (int j = 0; j < 8; ++j) {
        a00[j] = (_Float16)aval(t0, quad * 8 + j);
        a01[j] = (_Float16)aval(t0, 32 + quad * 8 + j);
        a10[j] = (_Float16)aval(t1, quad * 8 + j);
        a11[j] = (_Float16)aval(t1, 32 + quad * 8 + j);
    }

    auto mkbias = [&](int jh) -> f32x4 {
        f32x4 b = {0.f, 0.f, 0.f, 0.f};
        if (jh < HID) {
            b[0] = -1.44269504f * (b_ih[jh] + b_hh[jh]);
            b[1] = -1.44269504f * (b_ih[HID + jh] + b_hh[HID + jh]);
            b[2] =  2.88539008f * b_hh[2 * HID + jh];
            b[3] =  2.88539008f * b_ih[2 * HID + jh];
        }
        return b;
    };
    const f32x4 bias0 = mkbias(jh0);
    const f32x4 bias1 = mkbias(jh1);

    float h0 = 0.f, h1 = 0.f;

    // ---- x chunk staging: 128 timesteps, per-column contiguous ----
    auto stage_chunk = [&](int c) {
        const int n = tid >> 5;    // 0..15
        const int s = tid & 31;
        const float4* src = (const float4*)(x + ((size_t)(bb * NB + n) * TLEN + (size_t)c * CH) * IND);
#pragma unroll
        for (int r2 = 0; r2 < 8; ++r2) {
            const int fidx = s + 32 * r2;      // 0..255 float4 per column
            const float4 v = src[fidx];
            const int trel = fidx >> 1;
            const int d    = (fidx & 1) * 4;
            *(f16x4*)&x_lds[n * XSTR + trel * 8 + d] =
                f16x4{(_Float16)v.x, (_Float16)v.y, (_Float16)v.z, (_Float16)v.w};
        }
    };

    // wave 7: copy x(trel) [8 halves/col] from x_lds into B_lds[buf] rows 56..63
    auto copy_x = [&](int trel, int buf) {
        *(unsigned*)&B_lds[buf][m16 * BSTR + 56 + 2 * quad] =
            *(const unsigned*)&x_lds[m16 * XSTR + trel * 8 + 2 * quad];
    };

    // ---- init: zero both B buffers; stage chunk 0 ----
    {
        _Float16* bz = &B_lds[0][0];
        for (int idx = tid; idx < 2 * 16 * BSTR; idx += NTHR)
            bz[idx] = (_Float16)0.f;
    }
    stage_chunk(0);
    __syncthreads();

    const int bq = m16 * BSTR + quad * 8;   // bf0 offset within a buffer
    const int bw = m16 * BSTR;              // h write row base

    // 5-trans gates (scales prefolded upstream):
    //   r = rcp(1+2^c0); Z = 2^c1; E = 2^(c3 + r*c2)
    //   h' = (E*(Z+h) + (h-Z)) * rcp((E+1)*(Z+1))
    auto gates = [&](const f32x4& cc, float h) -> float {
        const float R2 = __builtin_amdgcn_exp2f(cc[0]);
        const float r  = __builtin_amdgcn_rcpf(1.0f + R2);
        const float Z2 = __builtin_amdgcn_exp2f(cc[1]);
        const float E  = __builtin_amdgcn_exp2f(cc[3] + r * cc[2]);
        const float num = E * (Z2 + h) + (h - Z2);
        const float den = (E + 1.0f) * (Z2 + 1.0f);
        return num * __builtin_amdgcn_rcpf(den);
    };

    // ---- the recurrence: waves 0-6 compute, wave 7 feeds x; 1 barrier/step ----
    for (int c = 0; c < 4; ++c) {
        if (c != 0) { stage_chunk(c); __syncthreads(); }
        if (wave == 7) copy_x(0, 0);        // seed x(c*128) into buf0
        __syncthreads();
#pragma unroll 4
        for (int i = 0; i < CH; i += 2) {
            // even step: read buf0, write buf1
            if (wave == 7) {
                copy_x(i + 1, 1);
            } else {
                const f16x8 bf0 = *(const f16x8*)&B_lds[0][bq];
                const f16x8 bf1 = *(const f16x8*)&B_lds[0][bq + 32];
                f32x4 c0 = __builtin_amdgcn_mfma_f32_16x16x32_f16(a00, bf0, bias0, 0, 0, 0);
                f32x4 c1 = __builtin_amdgcn_mfma_f32_16x16x32_f16(a10, bf0, bias1, 0, 0, 0);
                c0 = __builtin_amdgcn_mfma_f32_16x16x32_f16(a01, bf1, c0, 0, 0, 0);
                c1 = __builtin_amdgcn_mfma_f32_16x16x32_f16(a11, bf1, c1, 0, 0, 0);
                h0 = gates(c0, h0);
                h1 = gates(c1, h1);
                B_lds[1][bw + jh0] = (_Float16)h0;   // rows 50..55 stay exactly 0
                B_lds[1][bw + jh1] = (_Float16)h1;
            }
            __syncthreads();
            // odd step: read buf1, write buf0
            if (wave == 7) {
                if (i + 2 < CH) copy_x(i + 2, 0);    // x(128) seeded at next chunk
            } else {
                const f16x8 bf0 = *(const f16x8*)&B_lds[1][bq];
                const f16x8 bf1 = *(const f16x8*)&B_lds[1][bq + 32];
                f32x4 c0 = __builtin_amdgcn_mfma_f32_16x16x32_f16(a00, bf0, bias0, 0, 0, 0);
                f32x4 c1 = __builtin_amdgcn_mfma_f32_16x16x32_f16(a10, bf0, bias1, 0, 0, 0);
                c0 = __builtin_amdgcn_mfma_f32_16x16x32_f16(a01, bf1, c0, 0, 0, 0);
                c1 = __builtin_amdgcn_mfma_f32_16x16x32_f16(a11, bf1, c1, 0, 0, 0);
                h0 = gates(c0, h0);
                h1 = gates(c1, h1);
                B_lds[0][bw + jh0] = (_Float16)h0;
                B_lds[0][bw + jh1] = (_Float16)h1;
            }
            __syncthreads();
        }
    }

    // ---- head: out[n] = sum_jh h(jh,n) * W_out[jh] + b_out ----
    if (jh0 < HID) red[m16 * 56 + jh0] = h0 * W_out[jh0];
    if (jh1 < HID) red[m16 * 56 + jh1] = h1 * W_out[jh1];
    __syncthreads();
    if (tid < NB) {
        float s = b_out[0];
        for (int j = 0; j < HID; ++j) s += red[tid * 56 + j];
        out[bb * NB + tid] = s;
    }
}

extern "C" void kernel_launch(void* const* d_in, const int* in_sizes, int n_in,
                              void* d_out, int out_size, void* d_ws, size_t ws_size,
                              hipStream_t stream) {
    const float* x     = (const float*)d_in[0];
    const float* W_ih  = (const float*)d_in[1];
    const float* W_hh  = (const float*)d_in[2];
    const float* b_ih  = (const float*)d_in[3];
    const float* b_hh  = (const float*)d_in[4];
    const float* W_out = (const float*)d_in[5];
    const float* b_out = (const float*)d_in[6];
    float* out = (float*)d_out;

    const int B = in_sizes[0] / (TLEN * IND);   // 4096
    gru_mfma8<<<B / NB, NTHR, 0, stream>>>(x, W_ih, W_hh, b_ih, b_hh, W_out, b_out, out);
}

// Round 3
// 232.733 us; speedup vs baseline: 1.1333x; 1.0402x over previous
//
#include <hip/hip_runtime.h>

#define HID 50
#define IND 8
#define TLEN 512
#define NB 16        // batch columns per block — all 16 MFMA N cols real
#define CH 128       // x chunk timesteps staged in LDS (4 chunks/sequence)
#define XTS 136      // x_frag per-timestep stride in halves (272B: 17*16B, decorrelates banks)
#define NTHR 448     // 7 waves, 2 M-tiles each, tiles 0..13 (rows >=200 dead, self-zero)

typedef _Float16 f16x8 __attribute__((ext_vector_type(8)));
typedef _Float16 f16x4 __attribute__((ext_vector_type(4)));
typedef _Float16 f16x2 __attribute__((ext_vector_type(2)));
typedef float f32x4 __attribute__((ext_vector_type(4)));

// Round-13: B stored in MFMA-fragment order.
//  - h buffer = [kgrp 0..6][n 0..15][8 halves]; bf0 read = base + lane*16B
//    (1KB contiguous, conflict-free); bf1 h-part = base+1024 + lane*16B
//  - intra-slot k order permuted P=[0,4,1,5,2,6,3,7] so a lane's (jh0,jh1)
//    h pair is ADJACENT -> one packed b32 write/lane/step (A frags + x
//    staging use the same P, built once -> free)
//  - x(t) pre-staged per chunk in fragment order; quad==3 lanes read it
//    directly (per-lane address select) -> feeder wave gone, 7 waves
//  - rows 50..55: A cols zero + bias zero -> gates map h=0 -> h=0 (self-zero)
__global__ __launch_bounds__(NTHR, 1) void gru_mfma9(
    const float* __restrict__ x,      // [B, T, 8]
    const float* __restrict__ W_ih,   // [150, 8]
    const float* __restrict__ W_hh,   // [150, 50]
    const float* __restrict__ b_ih,   // [150]
    const float* __restrict__ b_hh,   // [150]
    const float* __restrict__ W_out,  // [1, 50]
    const float* __restrict__ b_out,  // [1]
    float* __restrict__ out)          // [B]
{
    const int tid  = threadIdx.x;     // 448 threads = 7 waves
    const int wave = tid >> 6;
    const int lane = tid & 63;
    const int m16  = lane & 15;
    const int quad = lane >> 4;
    const int bb   = blockIdx.x;

    const int t0  = 2 * wave;         // tiles; R = 16*t + m16; R = 4*jh + g
    const int t1  = 2 * wave + 1;
    const int jh0 = 8 * wave + quad;          // kgrp = wave, j = quad
    const int jh1 = 8 * wave + 4 + quad;      // kgrp = wave, j = 4 + quad

    // B buffers: 2 x [7 kgrps][16 slots][8 halves] = 2 x 896 halves (1792B each)
    __shared__ _Float16 B_lds[2 * 896];
    __shared__ _Float16 x_frag[CH * XTS];     // ~34.8 KB, fragment-ordered x
    __shared__ float    red[NB * 56];         // head scratch

    // intra-slot k permutation: register half p holds k-offset P[p]
    const int P[8] = {0, 4, 1, 5, 2, 6, 3, 7};

    // ---- one-time: A fragments + biases into VGPRs, scales prefolded ----
    auto aval = [&](int tt, int k) -> float {
        const int R  = 16 * tt + m16;
        const int rj = R >> 2;
        const int g  = R & 3;
        if (rj >= HID) return 0.f;
        const float sc = (g <= 1) ? -1.44269504f : 2.88539008f;
        float w = 0.f;
        if (g <= 1) {
            if (k < HID)      w = W_hh[(g * HID + rj) * HID + k];
            else if (k >= 56) w = W_ih[(g * HID + rj) * IND + (k - 56)];
        } else if (g == 2) {
            if (k < HID)      w = W_hh[(2 * HID + rj) * HID + k];
        } else {
            if (k >= 56)      w = W_ih[(2 * HID + rj) * IND + (k - 56)];
        }
        return sc * w;
    };

    f16x8 a00, a01, a10, a11;
#pragma unroll
    for (int p = 0; p < 8; ++p) {
        a00[p] = (_Float16)aval(t0, quad * 8 + P[p]);
        a01[p] = (_Float16)aval(t0, 32 + quad * 8 + P[p]);
        a10[p] = (_Float16)aval(t1, quad * 8 + P[p]);
        a11[p] = (_Float16)aval(t1, 32 + quad * 8 + P[p]);
    }

    auto mkbias = [&](int jh) -> f32x4 {
        f32x4 b = {0.f, 0.f, 0.f, 0.f};
        if (jh < HID) {
            b[0] = -1.44269504f * (b_ih[jh] + b_hh[jh]);
            b[1] = -1.44269504f * (b_ih[HID + jh] + b_hh[HID + jh]);
            b[2] =  2.88539008f * b_hh[2 * HID + jh];
            b[3] =  2.88539008f * b_ih[2 * HID + jh];
        }
        return b;
    };
    const f32x4 bias0 = mkbias(jh0);
    const f32x4 bias1 = mkbias(jh1);

    float h0 = 0.f, h1 = 0.f;

    // ---- x chunk staging: fragment order, permuted intra-slot ----
    // x_frag[trel*XTS + n*8 + p] = x[t][n][P[p]]
    auto stage_chunk = [&](int c) {
        for (int u = tid; u < NB * CH; u += NTHR) {      // 2048 units
            const int n    = u >> 7;
            const int trel = u & (CH - 1);
            const float4* s = (const float4*)(x + ((size_t)(bb * NB + n) * TLEN + (size_t)c * CH + trel) * IND);
            const float4 va = s[0];                       // d 0..3
            const float4 vb = s[1];                       // d 4..7
            const f16x4 lo = {(_Float16)va.x, (_Float16)vb.x, (_Float16)va.y, (_Float16)vb.y};
            const f16x4 hi = {(_Float16)va.z, (_Float16)vb.z, (_Float16)va.w, (_Float16)vb.w};
            *(f16x4*)&x_frag[trel * XTS + n * 8]     = lo;
            *(f16x4*)&x_frag[trel * XTS + n * 8 + 4] = hi;
        }
    };

    // ---- init: zero both B buffers; stage chunk 0 ----
    for (int idx = tid; idx < 2 * 896; idx += NTHR)
        B_lds[idx] = (_Float16)0.f;
    stage_chunk(0);
    __syncthreads();

    const int lane8 = lane * 8;                       // halves: lane*16B
    const _Float16* xq = &x_frag[m16 * 8];            // quad3 x base
    // write slot: kgrp=wave, slot=m16, halves 2q (h0) and 2q+1 (h1) — adjacent
    const int wad = wave * 128 + m16 * 8 + 2 * quad;  // halves within a buffer

    // 5-trans gates (scales prefolded): r = rcp(1+2^c0); Z = 2^c1;
    // E = 2^(c3 + r*c2); h' = (E*(Z+h) + (h-Z)) * rcp((E+1)*(Z+1))
    auto gates = [&](const f32x4& cc, float h) -> float {
        const float R2 = __builtin_amdgcn_exp2f(cc[0]);
        const float r  = __builtin_amdgcn_rcpf(1.0f + R2);
        const float Z2 = __builtin_amdgcn_exp2f(cc[1]);
        const float E  = __builtin_amdgcn_exp2f(cc[3] + r * cc[2]);
        const float num = E * (Z2 + h) + (h - Z2);
        const float den = (E + 1.0f) * (Z2 + 1.0f);
        return num * __builtin_amdgcn_rcpf(den);
    };

    auto step = [&](int i, int cur, int nxt) {
        _Float16* Bc = &B_lds[cur * 896];
        _Float16* Bn = &B_lds[nxt * 896];
        const f16x8 bf0 = *(const f16x8*)(Bc + lane8);
        const _Float16* p1 = (quad == 3) ? (xq + (size_t)i * XTS) : (Bc + 512 + lane8);
        const f16x8 bf1 = *(const f16x8*)p1;
        f32x4 c0 = __builtin_amdgcn_mfma_f32_16x16x32_f16(a00, bf0, bias0, 0, 0, 0);
        f32x4 c1 = __builtin_amdgcn_mfma_f32_16x16x32_f16(a10, bf0, bias1, 0, 0, 0);
        c0 = __builtin_amdgcn_mfma_f32_16x16x32_f16(a01, bf1, c0, 0, 0, 0);
        c1 = __builtin_amdgcn_mfma_f32_16x16x32_f16(a11, bf1, c1, 0, 0, 0);
        h0 = gates(c0, h0);
        h1 = gates(c1, h1);
        *(f16x2*)(Bn + wad) = f16x2{(_Float16)h0, (_Float16)h1};
        __syncthreads();
    };

    // ---- recurrence: 7 waves, 1 barrier/step ----
    for (int c = 0; c < 4; ++c) {
        if (c != 0) { stage_chunk(c); __syncthreads(); }
#pragma unroll 4
        for (int i = 0; i < CH; i += 2) {
            step(i,     0, 1);
            step(i + 1, 1, 0);
        }
    }

    // ---- head: out[n] = sum_jh h(jh,n) * W_out[jh] + b_out ----
    if (jh0 < HID) red[m16 * 56 + jh0] = h0 * W_out[jh0];
    if (jh1 < HID) red[m16 * 56 + jh1] = h1 * W_out[jh1];
    __syncthreads();
    if (tid < NB) {
        float s = b_out[0];
        for (int j = 0; j < HID; ++j) s += red[tid * 56 + j];
        out[bb * NB + tid] = s;
    }
}

extern "C" void kernel_launch(void* const* d_in, const int* in_sizes, int n_in,
                              void* d_out, int out_size, void* d_ws, size_t ws_size,
                              hipStream_t stream) {
    const float* x     = (const float*)d_in[0];
    const float* W_ih  = (const float*)d_in[1];
    const float* W_hh  = (const float*)d_in[2];
    const float* b_ih  = (const float*)d_in[3];
    const float* b_hh  = (const float*)d_in[4];
    const float* W_out = (const float*)d_in[5];
    const float* b_out = (const float*)d_in[6];
    float* out = (float*)d_out;

    const int B = in_sizes[0] / (TLEN * IND);   // 4096
    gru_mfma9<<<B / NB, NTHR, 0, stream>>>(x, W_ih, W_hh, b_ih, b_hh, W_out, b_out, out);
}